// Round 7
// baseline (414.539 us; speedup 1.0000x reference)
//
#include <hip/hip_runtime.h>

#define B_    1024
#define NG_   32
#define F_    16
#define ED_   6
#define EG_   256
#define ET_   262144
#define H1_   5
#define C1_   80
#define HC1_  400
#define C2_   160
#define OBS_  512

#define S1_   408   // LDS bf16 row stride (816B: 16B-aligned, 12-bank row skew)
#define SG_   400   // global bf16 row stride
#define MSG_S 161
#define SLOTS 24    // K3: packed ego-edge slots per block (2 graphs, mean ~16)

typedef unsigned short ushort8v __attribute__((ext_vector_type(8)));

__device__ __forceinline__ float bf2f(unsigned short u) {
  return __uint_as_float(((unsigned int)u) << 16);
}
__device__ __forceinline__ unsigned short f2bf(float f) {
  unsigned int u = __float_as_uint(f);
  u = u + 0x7FFFu + ((u >> 16) & 1u);   // RNE
  return (unsigned short)(u >> 16);
}
__device__ __forceinline__ float dot8(ushort8v hv, float4 wa, float4 wb, float acc) {
  acc = fmaf(bf2f(hv[0]), wa.x, acc);
  acc = fmaf(bf2f(hv[1]), wa.y, acc);
  acc = fmaf(bf2f(hv[2]), wa.z, acc);
  acc = fmaf(bf2f(hv[3]), wa.w, acc);
  acc = fmaf(bf2f(hv[4]), wb.x, acc);
  acc = fmaf(bf2f(hv[5]), wb.y, acc);
  acc = fmaf(bf2f(hv[6]), wb.z, acc);
  acc = fmaf(bf2f(hv[7]), wb.w, acc);
  return acc;
}

// ---------------------------------------------------------------------------
// K1: node transforms (waves 0-6) + bucket build (wave 7). One block/graph.
// ---------------------------------------------------------------------------
__global__ __launch_bounds__(512, 2)
void k1_transform_bucket(
    const float* __restrict__ x, const int* __restrict__ eidx,
    const float* __restrict__ Wl1, const float* __restrict__ bl1,
    const float* __restrict__ Wr1, const float* __restrict__ br1,
    unsigned short* __restrict__ xlg, unsigned short* __restrict__ xrg,
    int* __restrict__ eorder_g, int* __restrict__ bstart_g)
{
  __shared__ float xloc[NG_ * F_];
  __shared__ int   edst[EG_];
  const int b = blockIdx.x, tid = threadIdx.x;
  const int n0 = b * NG_, eb = b * EG_;

  if (tid < EG_) edst[tid] = eidx[ET_ + eb + tid] - n0;
  xloc[tid] = x[n0 * F_ + tid];            // NG_*F_ == 512 == blockDim
  __syncthreads();

  if (tid < 448) {
    for (int t = 0; t < 2; ++t) {
      const int ch = tid + t * 448;
      if (ch >= 800) break;
      const bool isL = (ch < 400);
      const int  c   = isL ? ch : ch - 400;
      const float* Wp = (isL ? Wl1 : Wr1) + c * F_;
      const float bias = isL ? bl1[c] : br1[c];
      unsigned short* dst = (isL ? xlg : xrg) + n0 * SG_ + c;
      float w[16];
#pragma unroll
      for (int qk = 0; qk < 4; ++qk) {
        float4 v = *(const float4*)(Wp + qk * 4);
        w[qk*4+0] = v.x; w[qk*4+1] = v.y; w[qk*4+2] = v.z; w[qk*4+3] = v.w;
      }
      for (int n = 0; n < NG_; n += 2) {
        const float* xa = &xloc[n * F_];
        float accA = bias, accB = bias;
#pragma unroll
        for (int qk = 0; qk < 4; ++qk) {
          float4 a  = *(const float4*)(xa + qk * 4);
          float4 bv = *(const float4*)(xa + F_ + qk * 4);
          accA = fmaf(a.x,  w[qk*4+0], accA); accA = fmaf(a.y,  w[qk*4+1], accA);
          accA = fmaf(a.z,  w[qk*4+2], accA); accA = fmaf(a.w,  w[qk*4+3], accA);
          accB = fmaf(bv.x, w[qk*4+0], accB); accB = fmaf(bv.y, w[qk*4+1], accB);
          accB = fmaf(bv.z, w[qk*4+2], accB); accB = fmaf(bv.w, w[qk*4+3], accB);
        }
        dst[n * SG_]       = f2bf(accA);
        dst[(n + 1) * SG_] = f2bf(accB);
      }
    }
  } else {
    const int lane = tid & 63;
    const int d    = lane & 31;
    const int half = lane >> 5;
    int cnt = 0;
    const int4* ed4 = (const int4*)edst;
    for (int i = 0; i < 32; ++i) {
      int4 v = ed4[half * 32 + i];
      cnt += (v.x == d) + (v.y == d) + (v.z == d) + (v.w == d);
    }
    const int cnt_lo = __shfl(cnt, d);
    const int total  = cnt + __shfl_xor(cnt, 32);
    int pre = total;
#pragma unroll
    for (int off = 1; off < 32; off <<= 1) {
      int tt = __shfl(pre, lane - off);
      if (d >= off) pre += tt;
    }
    const int start = pre - total;
    if (lane < 32) {
      bstart_g[b * 33 + d] = start;
      if (d == 31) bstart_g[b * 33 + 32] = pre;
    }
    int p = start + (half ? cnt_lo : 0);
    for (int i = 0; i < 32; ++i) {
      int4 v = ed4[half * 32 + i];
      const int e = half * 128 + i * 4;
      if (v.x == d) eorder_g[eb + p++] = e;
      if (v.y == d) eorder_g[eb + p++] = e + 1;
      if (v.z == d) eorder_g[eb + p++] = e + 2;
      if (v.w == d) eorder_g[eb + p++] = e + 3;
    }
  }
}

// ---------------------------------------------------------------------------
// K2: edge scores + segment softmax + aggregation. One block/graph.
// ---------------------------------------------------------------------------
__global__ __launch_bounds__(512, 2)
void k2_scores_aggregate(
    const unsigned short* __restrict__ xlg, const unsigned short* __restrict__ xrg,
    const int* __restrict__ eidx, const float* __restrict__ eattr,
    const float* __restrict__ We1, const float* __restrict__ att1,
    const float* __restrict__ bc1,
    const int* __restrict__ eorder_g, const int* __restrict__ bstart_g,
    unsigned short* __restrict__ hg)
{
  __shared__ __align__(16) unsigned short xl[NG_ * S1_];
  __shared__ __align__(16) unsigned short xr[NG_ * S1_];
  __shared__ float sc0[EG_ * H1_];
  __shared__ float sc1[EG_ * H1_];
  __shared__ float ea[EG_ * ED_];
  __shared__ int   esrc[EG_], edst[EG_], eorder[EG_];
  __shared__ int   bstart[NG_ + 1];
  __shared__ float deninv[NG_ * H1_];

  const int b = blockIdx.x, tid = threadIdx.x;
  const int n0 = b * NG_, eb = b * EG_;

  for (int i = tid; i < 3200; i += 512) {
    const bool isR = (i >= 1600);
    const int idx = isR ? i - 1600 : i;
    const int n = idx / 50, c8 = idx - n * 50;
    const ushort8v v = *(const ushort8v*)&(isR ? xrg : xlg)[(n0 + n) * SG_ + c8 * 8];
    *(ushort8v*)&(isR ? xr : xl)[n * S1_ + c8 * 8] = v;
  }
  if (tid < EG_) {
    esrc[tid]   = eidx[eb + tid] - n0;
    edst[tid]   = eidx[ET_ + eb + tid] - n0;
    eorder[tid] = eorder_g[eb + tid];
  }
  for (int i = tid; i < EG_ * ED_; i += 512) ea[i] = eattr[eb * ED_ + i];
  if (tid < NG_ + 1) bstart[tid] = bstart_g[b * 33 + tid];
  __syncthreads();

  {
    const int e = tid & 255;
    const int s = __builtin_amdgcn_readfirstlane((int)(tid >> 8) & 1);
    float* const scp = s ? sc1 : sc0;
    const int sl = esrc[e], dl = edst[e];
    const float e0 = ea[e*ED_+0], e1 = ea[e*ED_+1], e2 = ea[e*ED_+2];
    const float e3 = ea[e*ED_+3], e4 = ea[e*ED_+4], e5 = ea[e*ED_+5];
    const unsigned short* xlrow = &xl[sl * S1_ + s * 40];
    const unsigned short* xrrow = &xr[dl * S1_ + s * 40];
#pragma unroll
    for (int h = 0; h < H1_; ++h) {
      float sh = 0.f;
#pragma unroll
      for (int co = 0; co < 5; ++co) {
        const int coff  = h * C1_ + co * 8;
        const int cbase = coff + s * 40;
        ushort8v av = *(const ushort8v*)(xlrow + coff);
        ushort8v rv = *(const ushort8v*)(xrrow + coff);
#pragma unroll
        for (int u = 0; u < 8; ++u) {
          const float* wv6 = &We1[(cbase + u) * ED_];
          float t0 = fmaf(wv6[1], e1, wv6[0] * e0);
          float t1 = fmaf(wv6[3], e3, wv6[2] * e2);
          float t2 = fmaf(wv6[5], e5, wv6[4] * e4);
          float p = (bf2f(av[u]) + bf2f(rv[u])) + (t0 + (t1 + t2));
          p = fmaxf(p, 0.2f * p);
          sh = fmaf(p, att1[cbase + u], sh);
        }
      }
      scp[e * H1_ + h] = sh;
    }
  }
  __syncthreads();

  if (tid < NG_ * H1_) {
    const int d = tid & 31, h = tid >> 5;
    const int s0 = bstart[d], s1 = bstart[d + 1];
    float m = -INFINITY;
    for (int k = s0; k < s1; ++k) {
      const int e5i = eorder[k] * H1_ + h;
      m = fmaxf(m, sc0[e5i] + sc1[e5i]);
    }
    float den = 0.f;
    for (int k = s0; k < s1; ++k) {
      const int e5i = eorder[k] * H1_ + h;
      float t = expf(sc0[e5i] + sc1[e5i] - m);
      den += t;
      sc0[e5i] = t;
    }
    deninv[tid] = 1.f / (den + 1e-16f);
  }
  __syncthreads();

  for (int idx = tid; idx < NG_ * 50; idx += 512) {
    const int d  = idx / 50;
    const int co = idx - d * 50;
    const int c  = co * 8;
    const int h  = co / 10;
    const int s0 = bstart[d], s1 = bstart[d + 1];
    float acc[8] = {0.f,0.f,0.f,0.f,0.f,0.f,0.f,0.f};
    for (int k = s0; k < s1; ++k) {
      const int e = eorder[k];
      const float al = sc0[e * H1_ + h];
      ushort8v xv = *(const ushort8v*)(&xl[esrc[e] * S1_ + c]);
#pragma unroll
      for (int u = 0; u < 8; ++u) acc[u] = fmaf(al, bf2f(xv[u]), acc[u]);
    }
    const float inv = deninv[h * 32 + d];
    ushort8v hv;
#pragma unroll
    for (int u = 0; u < 8; ++u)
      hv[u] = f2bf(fmaxf(fmaf(acc[u], inv, bc1[c + u]), 0.f));
    *(ushort8v*)&hg[(n0 + d) * SG_ + c] = hv;
  }
}

// ---------------------------------------------------------------------------
// K3 (NEW): ego layer-2, 2 graphs per block, 512 blocks. All weight streams
// coalesced (wave = cc-strip; lanes = k-part x edge-slot; Wl2/Wr2 row read
// contiguously by the wave and broadcast across edge lanes). Edges of both
// graphs flat-packed into SLOTS; per-graph online softmax.
// ---------------------------------------------------------------------------
__global__ __launch_bounds__(512, 2)
void k3_ego_layer2(
    const int* __restrict__ eidx, const float* __restrict__ eattr,
    const unsigned short* __restrict__ hg,
    const float* __restrict__ Wl2, const float* __restrict__ bl2,
    const float* __restrict__ Wr2, const float* __restrict__ br2,
    const float* __restrict__ We2, const float* __restrict__ att2,
    const float* __restrict__ bc2,
    const int* __restrict__ eorder_g, const int* __restrict__ bstart_g,
    float* __restrict__ egoH)
{
  __shared__ __align__(16) unsigned short hrows[(SLOTS + 2) * S1_]; // slots + 2 ego rows
  __shared__ float msgAll[SLOTS * MSG_S];
  __shared__ float xr2v[2 * C2_];
  __shared__ float out2[2 * C2_];
  __shared__ float sArr[SLOTS], wArr[SLOTS];
  __shared__ float mrun[2], denrun[2], scal[2];
  __shared__ int   sEid[SLOTS], sGid[SLOTS], sSrc[SLOTS];
  __shared__ int   nEs[2];

  const int bb  = blockIdx.x;      // 0..511
  const int gb0 = bb * 2;          // first graph of the pair
  const int tid = threadIdx.x;
  const int wv  = tid >> 6;        // wave 0..7 -> cc strip [wv*20, wv*20+20)
  const int ln  = tid & 63;
  const int qq  = ln >> 3;         // k-part 0..7
  const int jv  = ln & 7;          // slot-within-8

  if (tid < 2) nEs[tid] = bstart_g[(gb0 + tid) * 33 + 1];
  // stage ego rows (slots SLOTS, SLOTS+1)
  for (int i = tid; i < 100; i += 512) {
    const int r = i / 50, c8 = i - r * 50;
    *(ushort8v*)&hrows[(SLOTS + r) * S1_ + c8 * 8] =
        *(const ushort8v*)&hg[((gb0 + r) * NG_) * SG_ + c8 * 8];
  }
  if (tid < 2 * C2_) out2[tid] = 0.f;
  if (tid < 2) { mrun[tid] = -INFINITY; denrun[tid] = 0.f; }
  __syncthreads();

  // ---- xr2v[g] = Wr2 @ h[ego_g] + br2 (coalesced wave-GEMM; jv&1 = graph) ----
  {
    const unsigned short* hr = &hrows[(SLOTS + (jv & 1)) * S1_];
    for (int p = 0; p < 10; ++p) {
      const int cc0 = wv * 20 + p * 2;
      const float* w0 = &Wr2[cc0 * HC1_];
      const float* w1 = w0 + HC1_;
      float a0 = 0.f, a1 = 0.f;
#pragma unroll
      for (int i = 0; i < 6; ++i) {
        const int k = qq * 8 + i * 64;
        ushort8v hv = *(const ushort8v*)(hr + k);
        a0 = dot8(hv, *(const float4*)(w0 + k), *(const float4*)(w0 + k + 4), a0);
        a1 = dot8(hv, *(const float4*)(w1 + k), *(const float4*)(w1 + k + 4), a1);
      }
      if (qq < 2) {
        const int k = 384 + qq * 8;
        ushort8v hv = *(const ushort8v*)(hr + k);
        a0 = dot8(hv, *(const float4*)(w0 + k), *(const float4*)(w0 + k + 4), a0);
        a1 = dot8(hv, *(const float4*)(w1 + k), *(const float4*)(w1 + k + 4), a1);
      }
      a0 += __shfl_xor(a0, 8); a0 += __shfl_xor(a0, 16); a0 += __shfl_xor(a0, 32);
      a1 += __shfl_xor(a1, 8); a1 += __shfl_xor(a1, 16); a1 += __shfl_xor(a1, 32);
      if (ln < 2) {
        xr2v[ln * C2_ + cc0]     = a0 + br2[cc0];
        xr2v[ln * C2_ + cc0 + 1] = a1 + br2[cc0 + 1];
      }
    }
  }

  const int nE0 = nEs[0], nE1 = nEs[1];
  const int L = nE0 + nE1;

  for (int c0 = 0; c0 < L; c0 += SLOTS) {
    const int nc  = min(SLOTS, L - c0);
    const int n0c = min(nc, max(0, nE0 - c0));   // slots [0,n0c) -> graph 0

    // slot meta
    if (tid < nc) {
      const int i = c0 + tid;
      const int g = (i < nE0) ? 0 : 1;
      const int j = (i < nE0) ? i : i - nE0;
      const int e = eorder_g[(gb0 + g) * EG_ + j];
      sEid[tid] = e;
      sGid[tid] = g;
      sSrc[tid] = eidx[(gb0 + g) * EG_ + e] - (gb0 + g) * NG_;
    }
    __syncthreads();
    // stage src rows
    for (int i = tid; i < nc * 50; i += 512) {
      const int r = i / 50, c8 = i - r * 50;
      *(ushort8v*)&hrows[r * S1_ + c8 * 8] =
          *(const ushort8v*)&hg[((gb0 + sGid[r]) * NG_ + sSrc[r]) * SG_ + c8 * 8];
    }
    __syncthreads();

    // ---- messages (coalesced wave-GEMM over slots) ----
    for (int jb = 0; jb < SLOTS; jb += 8) {
      if (jb >= nc) break;
      const int s    = jb + jv;
      const int srow = (s < nc) ? s : 0;
      const unsigned short* hr = &hrows[srow * S1_];
      for (int p = 0; p < 10; ++p) {
        const int cc0 = wv * 20 + p * 2;
        const float* w0 = &Wl2[cc0 * HC1_];
        const float* w1 = w0 + HC1_;
        float a0 = 0.f, a1 = 0.f;
#pragma unroll
        for (int i = 0; i < 6; ++i) {
          const int k = qq * 8 + i * 64;
          ushort8v hv = *(const ushort8v*)(hr + k);
          a0 = dot8(hv, *(const float4*)(w0 + k), *(const float4*)(w0 + k + 4), a0);
          a1 = dot8(hv, *(const float4*)(w1 + k), *(const float4*)(w1 + k + 4), a1);
        }
        if (qq < 2) {
          const int k = 384 + qq * 8;
          ushort8v hv = *(const ushort8v*)(hr + k);
          a0 = dot8(hv, *(const float4*)(w0 + k), *(const float4*)(w0 + k + 4), a0);
          a1 = dot8(hv, *(const float4*)(w1 + k), *(const float4*)(w1 + k + 4), a1);
        }
        a0 += __shfl_xor(a0, 8); a0 += __shfl_xor(a0, 16); a0 += __shfl_xor(a0, 32);
        a1 += __shfl_xor(a1, 8); a1 += __shfl_xor(a1, 16); a1 += __shfl_xor(a1, 32);
        if (ln < 8 && (jb + ln) < nc) {
          msgAll[(jb + ln) * MSG_S + cc0]     = a0 + bl2[cc0];
          msgAll[(jb + ln) * MSG_S + cc0 + 1] = a1 + bl2[cc0 + 1];
        }
      }
    }
    __syncthreads();

    // ---- scores: 8 lanes per slot ----
    if (tid < 8 * SLOTS) {
      const int s  = tid >> 3;
      const int q8 = tid & 7;
      float sv = 0.f;
      if (s < nc) {
        const int g = sGid[s];
        const float* eap = &eattr[((gb0 + g) * EG_ + sEid[s]) * ED_];
        const float e0 = eap[0], e1 = eap[1], e2 = eap[2];
        const float e3 = eap[3], e4 = eap[4], e5 = eap[5];
        const float* mrow = &msgAll[s * MSG_S];
        const float* xrv  = &xr2v[g * C2_];
        for (int i = 0; i < 20; ++i) {
          const int c2 = q8 * 20 + i;
          const float* wv6 = &We2[c2 * ED_];
          float t0 = fmaf(wv6[1], e1, wv6[0] * e0);
          float t1 = fmaf(wv6[3], e3, wv6[2] * e2);
          float t2 = fmaf(wv6[5], e5, wv6[4] * e4);
          float pp = mrow[c2] + xrv[c2] + (t0 + (t1 + t2));
          pp = fmaxf(pp, 0.2f * pp);
          sv = fmaf(pp, att2[c2], sv);
        }
      }
      sv += __shfl_xor(sv, 1); sv += __shfl_xor(sv, 2); sv += __shfl_xor(sv, 4);
      if (q8 == 0 && s < nc) sArr[s] = sv;
    }
    __syncthreads();

    // ---- per-graph online softmax merge (wave g handles graph g) ----
    if (tid < 128) {
      const int g = tid >> 6;          // 0 or 1
      const int j = tid & 31;          // lanes 32..63 duplicate lanes 0..31
      const int lo = g ? n0c : 0;
      const int hi = g ? nc  : n0c;
      const int idx = lo + j;
      const bool valid = (idx < hi);
      float sv = valid ? sArr[idx] : -INFINITY;
      float mg = sv;
      mg = fmaxf(mg, __shfl_xor(mg, 1));
      mg = fmaxf(mg, __shfl_xor(mg, 2));
      mg = fmaxf(mg, __shfl_xor(mg, 4));
      mg = fmaxf(mg, __shfl_xor(mg, 8));
      mg = fmaxf(mg, __shfl_xor(mg, 16));
      const float mold = mrun[g];
      const float mnew = fmaxf(mold, mg);
      float w = valid ? expf(sv - mnew) : 0.f;
      float dg = w;
      dg += __shfl_xor(dg, 1); dg += __shfl_xor(dg, 2); dg += __shfl_xor(dg, 4);
      dg += __shfl_xor(dg, 8); dg += __shfl_xor(dg, 16);
      if ((tid & 63) < 32 && valid) wArr[idx] = w;
      if ((tid & 63) == 0) {
        scal[g]   = (mold == -INFINITY) ? 0.f : expf(mold - mnew);
        denrun[g] = denrun[g] * scal[g] + dg;
        mrun[g]   = mnew;
      }
    }
    __syncthreads();

    // ---- accumulate ----
    if (tid < 2 * C2_) {
      const int g  = tid / C2_;
      const int cc = tid - g * C2_;
      const int lo = g ? n0c : 0;
      const int hi = g ? nc  : n0c;
      float o = out2[tid] * scal[g];
      for (int s = lo; s < hi; ++s) o = fmaf(wArr[s], msgAll[s * MSG_S + cc], o);
      out2[tid] = o;
    }
    __syncthreads();
  }

  if (tid < 2 * C2_) {
    const int g  = tid / C2_;
    const int cc = tid - g * C2_;
    const float v = out2[tid] / (denrun[g] + 1e-16f) + bc2[cc];
    egoH[(gb0 + g) * C2_ + cc] = fmaxf(v, 0.f);
  }
}

// ---------------------------------------------------------------------------
// K4: dense head + MLP (unchanged). 256 blocks x 512 threads.
// ---------------------------------------------------------------------------
__global__ __launch_bounds__(512, 2)
void mlp_head_kernel(
    const float* __restrict__ egoH,
    const float* __restrict__ Wd1, const float* __restrict__ bd1,
    const float* __restrict__ Wd2, const float* __restrict__ bd2,
    const float* __restrict__ Wf1, const float* __restrict__ bf1,
    const float* __restrict__ Wf2, const float* __restrict__ bf2,
    const float* __restrict__ Wm,  const float* __restrict__ bm,
    const float* __restrict__ Ws,  const float* __restrict__ bs,
    float* __restrict__ out)
{
  __shared__ float hE[4 * C2_];
  __shared__ float t1[4 * NG_];
  __shared__ float dbuf[4 * OBS_];
  __shared__ float f1b[4 * 256];
  __shared__ float f2b[4 * 256];

  const int g0  = blockIdx.x * 4;
  const int tid = threadIdx.x;

  for (int i = tid; i < 4 * C2_; i += 512) hE[i] = egoH[g0 * C2_ + i];
  __syncthreads();

  if (tid < 4 * NG_) {
    const int g = tid >> 5, o = tid & 31;
    float acc = bd1[o];
    const float* w  = &Wd1[o * C2_];
    const float* hp = &hE[g * C2_];
    for (int k = 0; k < C2_; k += 4) {
      float4 hv = *(const float4*)(hp + k);
      float4 wv = *(const float4*)(w + k);
      acc = fmaf(hv.x, wv.x, acc); acc = fmaf(hv.y, wv.y, acc);
      acc = fmaf(hv.z, wv.z, acc); acc = fmaf(hv.w, wv.w, acc);
    }
    t1[tid] = acc;
  }
  __syncthreads();

  for (int idx = tid; idx < 4 * OBS_; idx += 512) {
    const int g = idx >> 9, o = idx & 511;
    float acc = bd2[o];
    const float* w  = &Wd2[o * NG_];
    const float* tp = &t1[g * NG_];
#pragma unroll
    for (int k = 0; k < NG_; k += 4) {
      float4 tv = *(const float4*)(tp + k);
      float4 wv = *(const float4*)(w + k);
      acc = fmaf(tv.x, wv.x, acc); acc = fmaf(tv.y, wv.y, acc);
      acc = fmaf(tv.z, wv.z, acc); acc = fmaf(tv.w, wv.w, acc);
    }
    dbuf[idx] = tanhf(acc);
  }
  __syncthreads();

  {
    const int o = tid & 255, gg = tid >> 8;
    const float* w  = &Wf1[o * OBS_];
    const float* dA = &dbuf[(gg * 2 + 0) * OBS_];
    const float* dB = &dbuf[(gg * 2 + 1) * OBS_];
    float a0 = bf1[o], a1 = a0;
#pragma unroll 2
    for (int k = 0; k < OBS_; k += 4) {
      float4 wv = *(const float4*)(w + k);
      float4 xA = *(const float4*)(dA + k);
      float4 xB = *(const float4*)(dB + k);
      a0 = fmaf(xA.x, wv.x, a0); a0 = fmaf(xA.y, wv.y, a0);
      a0 = fmaf(xA.z, wv.z, a0); a0 = fmaf(xA.w, wv.w, a0);
      a1 = fmaf(xB.x, wv.x, a1); a1 = fmaf(xB.y, wv.y, a1);
      a1 = fmaf(xB.z, wv.z, a1); a1 = fmaf(xB.w, wv.w, a1);
    }
    f1b[(gg * 2 + 0) * 256 + o] = fmaxf(a0, 0.f);
    f1b[(gg * 2 + 1) * 256 + o] = fmaxf(a1, 0.f);
  }
  __syncthreads();

  {
    const int o = tid & 255, gg = tid >> 8;
    const float* w  = &Wf2[o * 256];
    const float* dA = &f1b[(gg * 2 + 0) * 256];
    const float* dB = &f1b[(gg * 2 + 1) * 256];
    float a0 = bf2[o], a1 = a0;
#pragma unroll 2
    for (int k = 0; k < 256; k += 4) {
      float4 wv = *(const float4*)(w + k);
      float4 xA = *(const float4*)(dA + k);
      float4 xB = *(const float4*)(dB + k);
      a0 = fmaf(xA.x, wv.x, a0); a0 = fmaf(xA.y, wv.y, a0);
      a0 = fmaf(xA.z, wv.z, a0); a0 = fmaf(xA.w, wv.w, a0);
      a1 = fmaf(xB.x, wv.x, a1); a1 = fmaf(xB.y, wv.y, a1);
      a1 = fmaf(xB.z, wv.z, a1); a1 = fmaf(xB.w, wv.w, a1);
    }
    f2b[(gg * 2 + 0) * 256 + o] = fmaxf(a0, 0.f);
    f2b[(gg * 2 + 1) * 256 + o] = fmaxf(a1, 0.f);
  }
  __syncthreads();

  if (tid < 16) {
    const int g  = tid >> 2;
    const int a  = (tid >> 1) & 1;
    const int hm = tid & 1;
    const float* fp = &f2b[g * 256];
    const float* w  = hm ? &Ws[a * 256] : &Wm[a * 256];
    float acc = hm ? bs[a] : bm[a];
    for (int k = 0; k < 256; ++k) acc = fmaf(fp[k], w[k], acc);
    if (hm == 0) out[(g0 + g) * 2 + a] = acc;
    else         out[2048 + (g0 + g) * 2 + a] = -5.0f + 3.5f * (tanhf(acc) + 1.0f);
  }
}

extern "C" void kernel_launch(void* const* d_in, const int* in_sizes, int n_in,
                              void* d_out, int out_size, void* d_ws, size_t ws_size,
                              hipStream_t stream) {
  const float* x     = (const float*)d_in[0];
  const int*   eidx  = (const int*)d_in[1];
  const float* eattr = (const float*)d_in[2];
  const float* Wl1 = (const float*)d_in[3];  const float* bl1 = (const float*)d_in[4];
  const float* Wr1 = (const float*)d_in[5];  const float* br1 = (const float*)d_in[6];
  const float* We1 = (const float*)d_in[7];  const float* att1= (const float*)d_in[8];
  const float* bc1 = (const float*)d_in[9];
  const float* Wl2 = (const float*)d_in[10]; const float* bl2 = (const float*)d_in[11];
  const float* Wr2 = (const float*)d_in[12]; const float* br2 = (const float*)d_in[13];
  const float* We2 = (const float*)d_in[14]; const float* att2= (const float*)d_in[15];
  const float* bc2 = (const float*)d_in[16];
  const float* Wd1 = (const float*)d_in[17]; const float* bd1 = (const float*)d_in[18];
  const float* Wd2 = (const float*)d_in[19]; const float* bd2 = (const float*)d_in[20];
  const float* Wf1 = (const float*)d_in[21]; const float* bf1 = (const float*)d_in[22];
  const float* Wf2 = (const float*)d_in[23]; const float* bf2 = (const float*)d_in[24];
  const float* Wm  = (const float*)d_in[25]; const float* bm  = (const float*)d_in[26];
  const float* Ws  = (const float*)d_in[27]; const float* bs  = (const float*)d_in[28];

  // workspace layout (~54.3 MB)
  unsigned short* xlg = (unsigned short*)d_ws;          // [32768][400] bf16 = 26.2 MB
  unsigned short* hg  = xlg + 32768 * SG_;              // xr, then h     = 26.2 MB
  int* eorder_g = (int*)(hg + 32768 * SG_);             // 1.05 MB
  int* bstart_g = eorder_g + ET_;                       // 132 KB
  float* egoH   = (float*)(bstart_g + B_ * 33);         // 640 KB

  k1_transform_bucket<<<B_, 512, 0, stream>>>(
      x, eidx, Wl1, bl1, Wr1, br1, xlg, hg, eorder_g, bstart_g);

  k2_scores_aggregate<<<B_, 512, 0, stream>>>(
      xlg, hg, eidx, eattr, We1, att1, bc1, eorder_g, bstart_g, hg);

  k3_ego_layer2<<<B_ / 2, 512, 0, stream>>>(
      eidx, eattr, hg, Wl2, bl2, Wr2, br2, We2, att2, bc2,
      eorder_g, bstart_g, egoH);

  mlp_head_kernel<<<B_ / 4, 512, 0, stream>>>(
      egoH, Wd1, bd1, Wd2, bd2, Wf1, bf1, Wf2, bf2, Wm, bm, Ws, bs,
      (float*)d_out);
}